// Round 1
// baseline (9267.277 us; speedup 1.0000x reference)
//
#include <hip/hip_runtime.h>
#include <math.h>

// GNN: 3x (SAGEConv -> TopKPool -> readout) + MLP head, all fp32.
// Design notes:
//  - msg = relu(lin(x_src)) depends only on src => per-NODE linear, not per-edge.
//  - scatter-max via CSR build (hist + scan + place) + per-node gather-max.
//  - top-k via 64-bit composite keys (monotone score bits | ~index) + 8-pass
//    radix select => exact jax.lax.top_k tie semantics; within-graph node order
//    is output-invariant so compaction order uses atomics.
//  - GEMM: 64-row tiles, LDS-transposed+XOR-swizzled A, wave-uniform W loads.
// Workspace budget ~165 MB.

typedef unsigned int uint;
typedef unsigned long long ull;

__device__ __forceinline__ float4 ld4(const float* p) { return *reinterpret_cast<const float4*>(p); }
__device__ __forceinline__ float2 ld2(const float* p) { return *reinterpret_cast<const float2*>(p); }

__device__ __forceinline__ uint mono32(float f) {
    uint b = __float_as_uint(f);
    return b ^ ((uint)((int)b >> 31) | 0x80000000u);
}

// out[m][c] = relu( sum_k A[m][k] * W[c][k] + bias[c] ), K=128 (A0) or 256 ([A0|A1])
template<int K>
__global__ __launch_bounds__(256, 4)
void gemm_relu(const float* __restrict__ A0, const float* __restrict__ A1,
               const float* __restrict__ W, const float* __restrict__ bias,
               float* __restrict__ out, int M)
{
    __shared__ float As[128][64];   // As[k][row ^ (k>>2)] swizzled
    const int tid = threadIdx.x;
    const int row0 = blockIdx.x * 64;
    const int lane = tid & 63;
    const int wid = __builtin_amdgcn_readfirstlane(tid >> 6);
    const int c0 = wid * 32;
    float acc[32];
#pragma unroll
    for (int j = 0; j < 32; ++j) acc[j] = 0.f;

#pragma unroll
    for (int ch = 0; ch < K / 128; ++ch) {
        const float* __restrict__ Ax = (ch == 0) ? A0 : A1;
        if (ch) __syncthreads();
#pragma unroll
        for (int it = 0; it < 8; ++it) {
            int idx = tid + it * 256;
            int row = idx >> 5;
            int kq = idx & 31;
            int grow = row0 + row;
            float4 v = make_float4(0.f, 0.f, 0.f, 0.f);
            if (grow < M) v = ld4(Ax + (size_t)grow * 128 + kq * 4);
            int sw = row ^ kq;
            As[kq * 4 + 0][sw] = v.x;
            As[kq * 4 + 1][sw] = v.y;
            As[kq * 4 + 2][sw] = v.z;
            As[kq * 4 + 3][sw] = v.w;
        }
        __syncthreads();
        const float* __restrict__ Wc = W + ch * 128;
#pragma unroll
        for (int kq = 0; kq < 32; ++kq) {
            int sw = lane ^ kq;
            float a0 = As[kq * 4 + 0][sw];
            float a1 = As[kq * 4 + 1][sw];
            float a2 = As[kq * 4 + 2][sw];
            float a3 = As[kq * 4 + 3][sw];
#pragma unroll
            for (int j = 0; j < 32; ++j) {
                float4 wv = ld4(Wc + (c0 + j) * K + kq * 4);  // wave-uniform -> s_load
                acc[j] = fmaf(a0, wv.x, acc[j]);
                acc[j] = fmaf(a1, wv.y, acc[j]);
                acc[j] = fmaf(a2, wv.z, acc[j]);
                acc[j] = fmaf(a3, wv.w, acc[j]);
            }
        }
    }
    int grow = row0 + lane;
    if (grow < M) {
        float* op = out + (size_t)grow * 128 + c0;
#pragma unroll
        for (int q = 0; q < 8; ++q) {
            float b0 = bias ? bias[c0 + q * 4 + 0] : 0.f;
            float b1 = bias ? bias[c0 + q * 4 + 1] : 0.f;
            float b2 = bias ? bias[c0 + q * 4 + 2] : 0.f;
            float b3 = bias ? bias[c0 + q * 4 + 3] : 0.f;
            float4 o;
            o.x = fmaxf(acc[q * 4 + 0] + b0, 0.f);
            o.y = fmaxf(acc[q * 4 + 1] + b1, 0.f);
            o.z = fmaxf(acc[q * 4 + 2] + b2, 0.f);
            o.w = fmaxf(acc[q * 4 + 3] + b3, 0.f);
            *reinterpret_cast<float4*>(op + q * 4) = o;
        }
    }
}

__global__ void edge_hist(const int* __restrict__ esrc, const int* __restrict__ edst,
                          int* __restrict__ deg, int E, int M)
{
    int i = blockIdx.x * 256 + threadIdx.x;
    if (i >= E) return;
    int s = esrc[i];
    if (s < M) atomicAdd(&deg[edst[i]], 1);   // invalid edges have s == d == M
}

__global__ void edge_place(const int* __restrict__ esrc, const int* __restrict__ edst,
                           int* __restrict__ cursor, int* __restrict__ csr, int E, int M)
{
    int i = blockIdx.x * 256 + threadIdx.x;
    if (i >= E) return;
    int s = esrc[i];
    if (s < M) {
        int pos = atomicAdd(&cursor[edst[i]], 1);
        csr[pos] = s;
    }
}

__global__ __launch_bounds__(256)
void scan_a(const int* __restrict__ deg, int* __restrict__ rowptr, int* __restrict__ bsum, int M)
{
    __shared__ int sh[256];
    int t = threadIdx.x;
    int base = blockIdx.x * 1024 + t * 4;
    int v0 = (base + 0 < M) ? deg[base + 0] : 0;
    int v1 = (base + 1 < M) ? deg[base + 1] : 0;
    int v2 = (base + 2 < M) ? deg[base + 2] : 0;
    int v3 = (base + 3 < M) ? deg[base + 3] : 0;
    int tsum = v0 + v1 + v2 + v3;
    sh[t] = tsum;
    __syncthreads();
    for (int off = 1; off < 256; off <<= 1) {
        int x = (t >= off) ? sh[t - off] : 0;
        __syncthreads();
        sh[t] += x;
        __syncthreads();
    }
    int run = sh[t] - tsum;
    if (t == 255) bsum[blockIdx.x] = sh[255];
    if (base + 0 < M) rowptr[base + 0] = run; run += v0;
    if (base + 1 < M) rowptr[base + 1] = run; run += v1;
    if (base + 2 < M) rowptr[base + 2] = run; run += v2;
    if (base + 3 < M) rowptr[base + 3] = run;
}

__global__ __launch_bounds__(256)
void scan_b(int* __restrict__ bsum, int NB)
{
    __shared__ int sh[256];
    int t = threadIdx.x;
    int v = (t < NB) ? bsum[t] : 0;
    sh[t] = v;
    __syncthreads();
    for (int off = 1; off < 256; off <<= 1) {
        int x = (t >= off) ? sh[t - off] : 0;
        __syncthreads();
        sh[t] += x;
        __syncthreads();
    }
    if (t < NB) bsum[t] = sh[t] - v;
}

__global__ void scan_c(int* __restrict__ rowptr, int* __restrict__ cursor,
                       const int* __restrict__ bsum, int M)
{
    int i = blockIdx.x * 256 + threadIdx.x;
    if (i < M) {
        int r = rowptr[i] + bsum[i >> 10];
        rowptr[i] = r;
        cursor[i] = r;
    }
}

// aggr[v] = max(y[v], max over incoming src y[src]); one wave per node, float2/lane
__global__ __launch_bounds__(256)
void aggr_max(const float* __restrict__ Y, const int* __restrict__ rowptr,
              const int* __restrict__ deg, const int* __restrict__ csr,
              float* __restrict__ A, int M)
{
    int wid = __builtin_amdgcn_readfirstlane((int)(threadIdx.x >> 6));
    int lane = threadIdx.x & 63;
    int node = blockIdx.x * 4 + wid;
    if (node >= M) return;
    int beg = rowptr[node];
    int end = beg + deg[node];
    float2 acc = ld2(Y + (size_t)node * 128 + lane * 2);
    int p = beg;
    for (; p + 4 <= end; p += 4) {
        int s0 = csr[p], s1 = csr[p + 1], s2 = csr[p + 2], s3 = csr[p + 3];
        float2 v0 = ld2(Y + (size_t)s0 * 128 + lane * 2);
        float2 v1 = ld2(Y + (size_t)s1 * 128 + lane * 2);
        float2 v2 = ld2(Y + (size_t)s2 * 128 + lane * 2);
        float2 v3 = ld2(Y + (size_t)s3 * 128 + lane * 2);
        acc.x = fmaxf(fmaxf(fmaxf(v0.x, v1.x), fmaxf(v2.x, v3.x)), acc.x);
        acc.y = fmaxf(fmaxf(fmaxf(v0.y, v1.y), fmaxf(v2.y, v3.y)), acc.y);
    }
    for (; p < end; ++p) {
        int s0 = csr[p];
        float2 v = ld2(Y + (size_t)s0 * 128 + lane * 2);
        acc.x = fmaxf(acc.x, v.x);
        acc.y = fmaxf(acc.y, v.y);
    }
    *reinterpret_cast<float2*>(A + (size_t)node * 128 + lane * 2) = acc;
}

__global__ __launch_bounds__(256)
void score_kernel(const float* __restrict__ H, const float* __restrict__ wp,
                  float* __restrict__ s, int M)
{
    int wid = threadIdx.x >> 6;
    int lane = threadIdx.x & 63;
    int node = blockIdx.x * 4 + wid;
    if (node >= M) return;
    float2 h = ld2(H + (size_t)node * 128 + lane * 2);
    float2 w = ld2(wp + lane * 2);
    float d = h.x * w.x + h.y * w.y;
    float nn = w.x * w.x + w.y * w.y;
    for (int off = 1; off < 64; off <<= 1) {
        d += __shfl_xor(d, off);
        nn += __shfl_xor(nn, off);
    }
    if (lane == 0) s[node] = d / sqrtf(nn);
}

// Per-graph exact top-k: composite key (mono(score)<<32)|~idx, MSB radix select.
__global__ __launch_bounds__(1024)
void topk_kernel(const float* __restrict__ s, ull* __restrict__ keys,
                 int* __restrict__ newpos, int* __restrict__ oldidx,
                 int n, int k, int Mout)
{
    __shared__ int hist[256];
    __shared__ ull sh_prefix;
    __shared__ int sh_need;
    __shared__ int sh_cnt;
    int g = blockIdx.x;
    int t = threadIdx.x;
    const float* sg = s + (size_t)g * n;
    ull* kg = keys + (size_t)g * n;
    for (int i = t; i < n; i += 1024) {
        uint m = mono32(sg[i]);
        kg[i] = ((ull)m << 32) | (uint)(~i);
    }
    if (t == 0) { sh_prefix = 0ull; sh_need = k; sh_cnt = 0; }
    __syncthreads();
    for (int pass = 7; pass >= 0; --pass) {
        int shift = pass * 8;
        if (t < 256) hist[t] = 0;
        __syncthreads();
        ull pref = sh_prefix;
        ull maskhi = (pass == 7) ? 0ull : (~0ull << (shift + 8));
        for (int i = t; i < n; i += 1024) {
            ull kk = kg[i];
            if ((kk & maskhi) == pref)
                atomicAdd(&hist[(int)((kk >> shift) & 255)], 1);
        }
        __syncthreads();
        if (t == 0) {
            int need = sh_need;
            int cum = 0, b = 255;
            for (; b > 0; --b) {
                if (cum + hist[b] >= need) break;
                cum += hist[b];
            }
            sh_prefix = pref | ((ull)b << shift);
            sh_need = need - cum;
        }
        __syncthreads();
    }
    ull pivot = sh_prefix;
    for (int i = t; i < n; i += 1024) {
        int gnode = g * n + i;
        if (kg[i] >= pivot) {
            int pos = g * k + atomicAdd(&sh_cnt, 1);
            newpos[gnode] = pos;
            oldidx[pos] = gnode;
        } else {
            newpos[gnode] = Mout;
        }
    }
}

__global__ __launch_bounds__(256)
void permute_kernel(const float* __restrict__ H, const float* __restrict__ s,
                    const int* __restrict__ oldidx, float* __restrict__ X, int Mout)
{
    int wid = __builtin_amdgcn_readfirstlane((int)(threadIdx.x >> 6));
    int lane = threadIdx.x & 63;
    int pos = blockIdx.x * 4 + wid;
    if (pos >= Mout) return;
    int old = oldidx[pos];
    float scv = tanhf(s[old]);
    float2 v = ld2(H + (size_t)old * 128 + lane * 2);
    v.x *= scv; v.y *= scv;
    *reinterpret_cast<float2*>(X + (size_t)pos * 128 + lane * 2) = v;
}

__global__ void remap_kernel(const int* __restrict__ ein_s, const int* __restrict__ ein_d,
                             int* __restrict__ eout_s, int* __restrict__ eout_d,
                             const int* __restrict__ newpos, int E, int Min, int Mout)
{
    int i = blockIdx.x * 256 + threadIdx.x;
    if (i >= E) return;
    int sv = ein_s[i], dv = ein_d[i];
    int ns = (sv < Min) ? newpos[sv] : Mout;
    int nd = (dv < Min) ? newpos[dv] : Mout;
    if (ns == Mout || nd == Mout) { ns = Mout; nd = Mout; }
    eout_s[i] = ns;
    eout_d[i] = nd;
}

__global__ __launch_bounds__(128)
void readout_kernel(const float* __restrict__ X, uint* __restrict__ zmax,
                    float* __restrict__ zsum, int k, int chunk)
{
    int g = blockIdx.x >> 5;    // 32 chunks per graph
    int c = blockIdx.x & 31;
    int f = threadIdx.x;
    int r0 = c * chunk;
    int r1 = r0 + chunk; if (r1 > k) r1 = k;
    float mx = -INFINITY, sm = 0.f;
    for (int r = r0; r < r1; ++r) {
        float v = X[(size_t)(g * k + r) * 128 + f];
        mx = fmaxf(mx, v);
        sm += v;
    }
    atomicMax(&zmax[g * 128 + f], mono32(mx));
    atomicAdd(&zsum[g * 128 + f], sm);
}

__global__ void accum_kernel(const uint* __restrict__ zmax, const float* __restrict__ zsum,
                             float* __restrict__ z, int k)
{
    int i = blockIdx.x * 256 + threadIdx.x;
    if (i >= 1024) return;
    int g = i >> 7, f = i & 127;
    uint u = zmax[i];
    float mx = (u & 0x80000000u) ? __uint_as_float(u ^ 0x80000000u) : __uint_as_float(~u);
    z[g * 256 + f] += mx;
    z[g * 256 + 128 + f] += zsum[i] / (float)k;
}

__global__ __launch_bounds__(256)
void mlp_kernel(const float* __restrict__ z,
                const float* __restrict__ Wl1, const float* __restrict__ bl1,
                const float* __restrict__ Wl2, const float* __restrict__ bl2,
                const float* __restrict__ Wl3, const float* __restrict__ bl3,
                float* __restrict__ out)
{
    __shared__ float zs[8 * 256];
    __shared__ float h1[8 * 128];
    __shared__ float h2[8 * 64];
    int t = threadIdx.x;
    for (int i = t; i < 2048; i += 256) zs[i] = z[i];
    __syncthreads();
    for (int o = t; o < 1024; o += 256) {
        int g = o >> 7, f = o & 127;
        const float* w = Wl1 + f * 256;
        const float* zz = zs + g * 256;
        float a = 0.f;
        for (int j = 0; j < 256; ++j) a = fmaf(zz[j], w[j], a);
        h1[o] = fmaxf(a + bl1[f], 0.f);
    }
    __syncthreads();
    for (int o = t; o < 512; o += 256) {
        int g = o >> 6, f = o & 63;
        const float* w = Wl2 + f * 128;
        const float* hh = h1 + g * 128;
        float a = 0.f;
        for (int j = 0; j < 128; ++j) a = fmaf(hh[j], w[j], a);
        h2[o] = fmaxf(a + bl2[f], 0.f);
    }
    __syncthreads();
    if (t < 8) {
        const float* hh = h2 + t * 64;
        float a = 0.f;
        for (int j = 0; j < 64; ++j) a = fmaf(hh[j], Wl3[j], a);
        a += bl3[0];
        out[t] = 1.f / (1.f + expf(-a));
    }
}

extern "C" void kernel_launch(void* const* d_in, const int* in_sizes, int n_in,
                              void* d_out, int out_size, void* d_ws, size_t ws_size,
                              hipStream_t stream)
{
    const float* x0 = (const float*)d_in[0];
    const int* e0 = (const int*)d_in[1];
    const int E = in_sizes[1] / 2;
    const int N = in_sizes[0] / 128;
    const int B = 8;

    char* p = (char*)d_ws;
    auto carve = [&](size_t bytes) -> char* {
        char* r = p;
        p += (bytes + 255) & ~(size_t)255;
        return r;
    };
    float* X      = (float*)carve((size_t)80000 * 128 * 4);  // pooled x (<= 80000 rows)
    float* Y      = (float*)carve((size_t)100000 * 128 * 4); // y, then h
    float* G      = (float*)carve((size_t)100000 * 128 * 4); // aggr
    int*   E2s    = (int*)carve((size_t)E * 4);
    int*   E2d    = (int*)carve((size_t)E * 4);
    int*   csr    = (int*)carve((size_t)E * 4);
    int*   deg    = (int*)carve(100000 * 4);
    int*   rowptr = (int*)carve(100000 * 4);
    int*   cursor = (int*)carve(100000 * 4);
    int*   bsum   = (int*)carve(256 * 4);
    ull*   keys   = (ull*)carve((size_t)100000 * 8);
    float* sc     = (float*)carve(100000 * 4);
    int*   newpos = (int*)carve(100000 * 4);
    int*   oldidx = (int*)carve(80000 * 4);
    uint*  zmaxu  = (uint*)carve(1024 * 4);
    float* zsum   = (float*)carve(1024 * 4);
    float* z      = (float*)carve(2048 * 4);

    hipMemsetAsync(z, 0, 2048 * 4, stream);

    const float* xin = x0;
    const int* es = e0;
    const int* ed = e0 + E;
    int M = N;
    int eb = (E + 255) / 256;

    for (int l = 0; l < 3; ++l) {
        int n = M / B;
        int k = (int)ceil(0.8 * (double)n);
        int Mout = B * k;
        const float* Wlin = (const float*)d_in[2 + 4 * l];
        const float* blin = (const float*)d_in[3 + 4 * l];
        const float* Wupd = (const float*)d_in[4 + 4 * l];
        const float* wp   = (const float*)d_in[5 + 4 * l];
        int gb = (M + 63) / 64;
        int nb = (M + 1023) / 1024;

        // conv
        gemm_relu<128><<<gb, 256, 0, stream>>>(xin, nullptr, Wlin, blin, Y, M);
        hipMemsetAsync(deg, 0, (size_t)M * 4, stream);
        edge_hist<<<eb, 256, 0, stream>>>(es, ed, deg, E, M);
        scan_a<<<nb, 256, 0, stream>>>(deg, rowptr, bsum, M);
        scan_b<<<1, 256, 0, stream>>>(bsum, nb);
        scan_c<<<(M + 255) / 256, 256, 0, stream>>>(rowptr, cursor, bsum, M);
        edge_place<<<eb, 256, 0, stream>>>(es, ed, cursor, csr, E, M);
        aggr_max<<<(M + 3) / 4, 256, 0, stream>>>(Y, rowptr, deg, csr, G, M);
        gemm_relu<256><<<gb, 256, 0, stream>>>(G, xin, Wupd, nullptr, Y, M);

        // pool
        score_kernel<<<(M + 3) / 4, 256, 0, stream>>>(Y, wp, sc, M);
        topk_kernel<<<B, 1024, 0, stream>>>(sc, keys, newpos, oldidx, n, k, Mout);
        permute_kernel<<<(Mout + 3) / 4, 256, 0, stream>>>(Y, sc, oldidx, X, Mout);

        // readout (accumulate into z)
        hipMemsetAsync(zmaxu, 0, 1024 * 4, stream);
        hipMemsetAsync(zsum, 0, 1024 * 4, stream);
        int chunk = (k + 31) / 32;
        readout_kernel<<<256, 128, 0, stream>>>(X, zmaxu, zsum, k, chunk);
        accum_kernel<<<4, 256, 0, stream>>>(zmaxu, zsum, z, k);

        if (l < 2) {
            remap_kernel<<<eb, 256, 0, stream>>>(es, ed, E2s, E2d, newpos, E, M, Mout);
            es = E2s; ed = E2d;
        }
        xin = X;
        M = Mout;
    }

    mlp_kernel<<<1, 256, 0, stream>>>(z,
        (const float*)d_in[14], (const float*)d_in[15],
        (const float*)d_in[16], (const float*)d_in[17],
        (const float*)d_in[18], (const float*)d_in[19],
        (float*)d_out);
}

// Round 2
// 1550.978 us; speedup vs baseline: 5.9751x; 5.9751x over previous
//
#include <hip/hip_runtime.h>
#include <math.h>

// GNN: 3x (SAGEConv -> TopKPool -> readout) + MLP head, all fp32.
//  - msg = relu(lin(x_src)) depends only on src => per-NODE linear, not per-edge.
//  - scatter-max via CSR build (hist + scan + place) + per-node gather-max.
//  - top-k via 64-bit composite keys + 8-pass radix select (exact jax tie order);
//    within-graph compaction order is output-invariant (readout is max/mean,
//    conv is permutation-equivariant, edges remapped consistently).
//  - GEMM: 128x128 block tile, 8x8/thread register tile, A+W staged in LDS
//    (k-major, pad 132 => 16B-aligned b128 reads, conflict-free), K-tile 32.
//    launch_bounds(256,2): acc 64 + operands ~70 VGPR, cap 256 -> no spill
//    (round-1 version spilled acc -> 2.4 GB scratch writes per dispatch).

typedef unsigned int uint;
typedef unsigned long long ull;

__device__ __forceinline__ float4 ld4(const float* p) { return *reinterpret_cast<const float4*>(p); }
__device__ __forceinline__ float2 ld2(const float* p) { return *reinterpret_cast<const float2*>(p); }

__device__ __forceinline__ uint mono32(float f) {
    uint b = __float_as_uint(f);
    return b ^ ((uint)((int)b >> 31) | 0x80000000u);
}

// out[m][c] = relu( sum_k A[m][k] * W[c][k] + bias[c] ), K=128 (A0) or 256 ([A0|A1])
template<int K>
__global__ __launch_bounds__(256, 2)
void gemm_relu(const float* __restrict__ A0, const float* __restrict__ A1,
               const float* __restrict__ W, const float* __restrict__ bias,
               float* __restrict__ out, int M)
{
    __shared__ __align__(16) float As[32][132];   // [k][row], bank stride 4
    __shared__ __align__(16) float Ws[32][132];   // [k][col]
    const int tid = threadIdx.x;
    const int tx = tid & 15;    // col group: cols tx*8 .. +8
    const int ty = tid >> 4;    // row group: rows ty*8 .. +8
    const int row0 = blockIdx.x * 128;

    float acc[8][8];
#pragma unroll
    for (int i = 0; i < 8; ++i)
#pragma unroll
        for (int j = 0; j < 8; ++j) acc[i][j] = 0.f;

#pragma unroll
    for (int ch = 0; ch < K / 128; ++ch) {
        const float* __restrict__ Ax = ch ? A1 : A0;
        const float* __restrict__ Wc = W + ch * 128;
#pragma unroll
        for (int kt = 0; kt < 4; ++kt) {
            // stage A tile: 128 rows x 32 k  (transpose into As[k][row])
#pragma unroll
            for (int it = 0; it < 4; ++it) {
                int idx = tid + it * 256;
                int row = idx >> 3;
                int kq = idx & 7;
                int grow = row0 + row;
                float4 v = make_float4(0.f, 0.f, 0.f, 0.f);
                if (grow < M) v = ld4(Ax + (size_t)grow * 128 + kt * 32 + kq * 4);
                As[kq * 4 + 0][row] = v.x;
                As[kq * 4 + 1][row] = v.y;
                As[kq * 4 + 2][row] = v.z;
                As[kq * 4 + 3][row] = v.w;
            }
            // stage W tile: 128 cols x 32 k  (transpose into Ws[k][col])
#pragma unroll
            for (int it = 0; it < 4; ++it) {
                int idx = tid + it * 256;
                int col = idx >> 3;
                int kq = idx & 7;
                float4 v = ld4(Wc + (size_t)col * K + kt * 32 + kq * 4);
                Ws[kq * 4 + 0][col] = v.x;
                Ws[kq * 4 + 1][col] = v.y;
                Ws[kq * 4 + 2][col] = v.z;
                Ws[kq * 4 + 3][col] = v.w;
            }
            __syncthreads();
#pragma unroll 4
            for (int k = 0; k < 32; ++k) {
                float4 a0 = *reinterpret_cast<const float4*>(&As[k][ty * 8]);
                float4 a1 = *reinterpret_cast<const float4*>(&As[k][ty * 8 + 4]);
                float4 w0 = *reinterpret_cast<const float4*>(&Ws[k][tx * 8]);
                float4 w1 = *reinterpret_cast<const float4*>(&Ws[k][tx * 8 + 4]);
                float av[8] = {a0.x, a0.y, a0.z, a0.w, a1.x, a1.y, a1.z, a1.w};
                float wv[8] = {w0.x, w0.y, w0.z, w0.w, w1.x, w1.y, w1.z, w1.w};
#pragma unroll
                for (int i = 0; i < 8; ++i)
#pragma unroll
                    for (int j = 0; j < 8; ++j)
                        acc[i][j] = fmaf(av[i], wv[j], acc[i][j]);
            }
            __syncthreads();
        }
    }

    float b[8];
#pragma unroll
    for (int j = 0; j < 8; ++j) b[j] = bias ? bias[tx * 8 + j] : 0.f;
#pragma unroll
    for (int i = 0; i < 8; ++i) {
        int grow = row0 + ty * 8 + i;
        if (grow < M) {
            float* op = out + (size_t)grow * 128 + tx * 8;
            float4 o0, o1;
            o0.x = fmaxf(acc[i][0] + b[0], 0.f);
            o0.y = fmaxf(acc[i][1] + b[1], 0.f);
            o0.z = fmaxf(acc[i][2] + b[2], 0.f);
            o0.w = fmaxf(acc[i][3] + b[3], 0.f);
            o1.x = fmaxf(acc[i][4] + b[4], 0.f);
            o1.y = fmaxf(acc[i][5] + b[5], 0.f);
            o1.z = fmaxf(acc[i][6] + b[6], 0.f);
            o1.w = fmaxf(acc[i][7] + b[7], 0.f);
            *reinterpret_cast<float4*>(op) = o0;
            *reinterpret_cast<float4*>(op + 4) = o1;
        }
    }
}

__global__ void edge_hist(const int* __restrict__ esrc, const int* __restrict__ edst,
                          int* __restrict__ deg, int E, int M)
{
    int i = blockIdx.x * 256 + threadIdx.x;
    if (i >= E) return;
    int s = esrc[i];
    if (s < M) atomicAdd(&deg[edst[i]], 1);   // invalid edges have s == d == M
}

__global__ void edge_place(const int* __restrict__ esrc, const int* __restrict__ edst,
                           int* __restrict__ cursor, int* __restrict__ csr, int E, int M)
{
    int i = blockIdx.x * 256 + threadIdx.x;
    if (i >= E) return;
    int s = esrc[i];
    if (s < M) {
        int pos = atomicAdd(&cursor[edst[i]], 1);
        csr[pos] = s;
    }
}

__global__ __launch_bounds__(256)
void scan_a(const int* __restrict__ deg, int* __restrict__ rowptr, int* __restrict__ bsum, int M)
{
    __shared__ int sh[256];
    int t = threadIdx.x;
    int base = blockIdx.x * 1024 + t * 4;
    int v0 = (base + 0 < M) ? deg[base + 0] : 0;
    int v1 = (base + 1 < M) ? deg[base + 1] : 0;
    int v2 = (base + 2 < M) ? deg[base + 2] : 0;
    int v3 = (base + 3 < M) ? deg[base + 3] : 0;
    int tsum = v0 + v1 + v2 + v3;
    sh[t] = tsum;
    __syncthreads();
    for (int off = 1; off < 256; off <<= 1) {
        int x = (t >= off) ? sh[t - off] : 0;
        __syncthreads();
        sh[t] += x;
        __syncthreads();
    }
    int run = sh[t] - tsum;
    if (t == 255) bsum[blockIdx.x] = sh[255];
    if (base + 0 < M) rowptr[base + 0] = run; run += v0;
    if (base + 1 < M) rowptr[base + 1] = run; run += v1;
    if (base + 2 < M) rowptr[base + 2] = run; run += v2;
    if (base + 3 < M) rowptr[base + 3] = run;
}

__global__ __launch_bounds__(256)
void scan_b(int* __restrict__ bsum, int NB)
{
    __shared__ int sh[256];
    int t = threadIdx.x;
    int v = (t < NB) ? bsum[t] : 0;
    sh[t] = v;
    __syncthreads();
    for (int off = 1; off < 256; off <<= 1) {
        int x = (t >= off) ? sh[t - off] : 0;
        __syncthreads();
        sh[t] += x;
        __syncthreads();
    }
    if (t < NB) bsum[t] = sh[t] - v;
}

__global__ void scan_c(int* __restrict__ rowptr, int* __restrict__ cursor,
                       const int* __restrict__ bsum, int M)
{
    int i = blockIdx.x * 256 + threadIdx.x;
    if (i < M) {
        int r = rowptr[i] + bsum[i >> 10];
        rowptr[i] = r;
        cursor[i] = r;
    }
}

// aggr[v] = max(y[v], max over incoming src y[src]); one wave per node, float2/lane
__global__ __launch_bounds__(256)
void aggr_max(const float* __restrict__ Y, const int* __restrict__ rowptr,
              const int* __restrict__ deg, const int* __restrict__ csr,
              float* __restrict__ A, int M)
{
    int wid = __builtin_amdgcn_readfirstlane((int)(threadIdx.x >> 6));
    int lane = threadIdx.x & 63;
    int node = blockIdx.x * 4 + wid;
    if (node >= M) return;
    int beg = rowptr[node];
    int end = beg + deg[node];
    float2 acc = ld2(Y + (size_t)node * 128 + lane * 2);
    int p = beg;
    for (; p + 4 <= end; p += 4) {
        int s0 = csr[p], s1 = csr[p + 1], s2 = csr[p + 2], s3 = csr[p + 3];
        float2 v0 = ld2(Y + (size_t)s0 * 128 + lane * 2);
        float2 v1 = ld2(Y + (size_t)s1 * 128 + lane * 2);
        float2 v2 = ld2(Y + (size_t)s2 * 128 + lane * 2);
        float2 v3 = ld2(Y + (size_t)s3 * 128 + lane * 2);
        acc.x = fmaxf(fmaxf(fmaxf(v0.x, v1.x), fmaxf(v2.x, v3.x)), acc.x);
        acc.y = fmaxf(fmaxf(fmaxf(v0.y, v1.y), fmaxf(v2.y, v3.y)), acc.y);
    }
    for (; p < end; ++p) {
        int s0 = csr[p];
        float2 v = ld2(Y + (size_t)s0 * 128 + lane * 2);
        acc.x = fmaxf(acc.x, v.x);
        acc.y = fmaxf(acc.y, v.y);
    }
    *reinterpret_cast<float2*>(A + (size_t)node * 128 + lane * 2) = acc;
}

__global__ __launch_bounds__(256)
void score_kernel(const float* __restrict__ H, const float* __restrict__ wp,
                  float* __restrict__ s, int M)
{
    int wid = threadIdx.x >> 6;
    int lane = threadIdx.x & 63;
    int node = blockIdx.x * 4 + wid;
    if (node >= M) return;
    float2 h = ld2(H + (size_t)node * 128 + lane * 2);
    float2 w = ld2(wp + lane * 2);
    float d = h.x * w.x + h.y * w.y;
    float nn = w.x * w.x + w.y * w.y;
    for (int off = 1; off < 64; off <<= 1) {
        d += __shfl_xor(d, off);
        nn += __shfl_xor(nn, off);
    }
    if (lane == 0) s[node] = d / sqrtf(nn);
}

// Per-graph exact top-k: composite key (mono(score)<<32)|~idx, MSB radix select.
__global__ __launch_bounds__(1024)
void topk_kernel(const float* __restrict__ s, ull* __restrict__ keys,
                 int* __restrict__ newpos, int* __restrict__ oldidx,
                 int n, int k, int Mout)
{
    __shared__ int hist[256];
    __shared__ ull sh_prefix;
    __shared__ int sh_need;
    __shared__ int sh_cnt;
    int g = blockIdx.x;
    int t = threadIdx.x;
    const float* sg = s + (size_t)g * n;
    ull* kg = keys + (size_t)g * n;
    for (int i = t; i < n; i += 1024) {
        uint m = mono32(sg[i]);
        kg[i] = ((ull)m << 32) | (uint)(~i);
    }
    if (t == 0) { sh_prefix = 0ull; sh_need = k; sh_cnt = 0; }
    __syncthreads();
    for (int pass = 7; pass >= 0; --pass) {
        int shift = pass * 8;
        if (t < 256) hist[t] = 0;
        __syncthreads();
        ull pref = sh_prefix;
        ull maskhi = (pass == 7) ? 0ull : (~0ull << (shift + 8));
        for (int i = t; i < n; i += 1024) {
            ull kk = kg[i];
            if ((kk & maskhi) == pref)
                atomicAdd(&hist[(int)((kk >> shift) & 255)], 1);
        }
        __syncthreads();
        if (t == 0) {
            int need = sh_need;
            int cum = 0, b = 255;
            for (; b > 0; --b) {
                if (cum + hist[b] >= need) break;
                cum += hist[b];
            }
            sh_prefix = pref | ((ull)b << shift);
            sh_need = need - cum;
        }
        __syncthreads();
    }
    ull pivot = sh_prefix;
    for (int i = t; i < n; i += 1024) {
        int gnode = g * n + i;
        if (kg[i] >= pivot) {
            int pos = g * k + atomicAdd(&sh_cnt, 1);
            newpos[gnode] = pos;
            oldidx[pos] = gnode;
        } else {
            newpos[gnode] = Mout;
        }
    }
}

__global__ __launch_bounds__(256)
void permute_kernel(const float* __restrict__ H, const float* __restrict__ s,
                    const int* __restrict__ oldidx, float* __restrict__ X, int Mout)
{
    int wid = __builtin_amdgcn_readfirstlane((int)(threadIdx.x >> 6));
    int lane = threadIdx.x & 63;
    int pos = blockIdx.x * 4 + wid;
    if (pos >= Mout) return;
    int old = oldidx[pos];
    float scv = tanhf(s[old]);
    float2 v = ld2(H + (size_t)old * 128 + lane * 2);
    v.x *= scv; v.y *= scv;
    *reinterpret_cast<float2*>(X + (size_t)pos * 128 + lane * 2) = v;
}

__global__ void remap_kernel(const int* __restrict__ ein_s, const int* __restrict__ ein_d,
                             int* __restrict__ eout_s, int* __restrict__ eout_d,
                             const int* __restrict__ newpos, int E, int Min, int Mout)
{
    int i = blockIdx.x * 256 + threadIdx.x;
    if (i >= E) return;
    int sv = ein_s[i], dv = ein_d[i];
    int ns = (sv < Min) ? newpos[sv] : Mout;
    int nd = (dv < Min) ? newpos[dv] : Mout;
    if (ns == Mout || nd == Mout) { ns = Mout; nd = Mout; }
    eout_s[i] = ns;
    eout_d[i] = nd;
}

__global__ __launch_bounds__(128)
void readout_kernel(const float* __restrict__ X, uint* __restrict__ zmax,
                    float* __restrict__ zsum, int k, int chunk)
{
    int g = blockIdx.x >> 5;    // 32 chunks per graph
    int c = blockIdx.x & 31;
    int f = threadIdx.x;
    int r0 = c * chunk;
    int r1 = r0 + chunk; if (r1 > k) r1 = k;
    float mx = -INFINITY, sm = 0.f;
    for (int r = r0; r < r1; ++r) {
        float v = X[(size_t)(g * k + r) * 128 + f];
        mx = fmaxf(mx, v);
        sm += v;
    }
    atomicMax(&zmax[g * 128 + f], mono32(mx));
    atomicAdd(&zsum[g * 128 + f], sm);
}

__global__ void accum_kernel(const uint* __restrict__ zmax, const float* __restrict__ zsum,
                             float* __restrict__ z, int k)
{
    int i = blockIdx.x * 256 + threadIdx.x;
    if (i >= 1024) return;
    int g = i >> 7, f = i & 127;
    uint u = zmax[i];
    float mx = (u & 0x80000000u) ? __uint_as_float(u ^ 0x80000000u) : __uint_as_float(~u);
    z[g * 256 + f] += mx;
    z[g * 256 + 128 + f] += zsum[i] / (float)k;
}

__global__ __launch_bounds__(256)
void mlp_kernel(const float* __restrict__ z,
                const float* __restrict__ Wl1, const float* __restrict__ bl1,
                const float* __restrict__ Wl2, const float* __restrict__ bl2,
                const float* __restrict__ Wl3, const float* __restrict__ bl3,
                float* __restrict__ out)
{
    __shared__ float zs[8 * 256];
    __shared__ float h1[8 * 128];
    __shared__ float h2[8 * 64];
    int t = threadIdx.x;
    for (int i = t; i < 2048; i += 256) zs[i] = z[i];
    __syncthreads();
    for (int o = t; o < 1024; o += 256) {
        int g = o >> 7, f = o & 127;
        const float* w = Wl1 + f * 256;
        const float* zz = zs + g * 256;
        float a = 0.f;
        for (int j = 0; j < 256; ++j) a = fmaf(zz[j], w[j], a);
        h1[o] = fmaxf(a + bl1[f], 0.f);
    }
    __syncthreads();
    for (int o = t; o < 512; o += 256) {
        int g = o >> 6, f = o & 63;
        const float* w = Wl2 + f * 128;
        const float* hh = h1 + g * 128;
        float a = 0.f;
        for (int j = 0; j < 128; ++j) a = fmaf(hh[j], w[j], a);
        h2[o] = fmaxf(a + bl2[f], 0.f);
    }
    __syncthreads();
    if (t < 8) {
        const float* hh = h2 + t * 64;
        float a = 0.f;
        for (int j = 0; j < 64; ++j) a = fmaf(hh[j], Wl3[j], a);
        a += bl3[0];
        out[t] = 1.f / (1.f + expf(-a));
    }
}

extern "C" void kernel_launch(void* const* d_in, const int* in_sizes, int n_in,
                              void* d_out, int out_size, void* d_ws, size_t ws_size,
                              hipStream_t stream)
{
    const float* x0 = (const float*)d_in[0];
    const int* e0 = (const int*)d_in[1];
    const int E = in_sizes[1] / 2;
    const int N = in_sizes[0] / 128;
    const int B = 8;

    char* p = (char*)d_ws;
    auto carve = [&](size_t bytes) -> char* {
        char* r = p;
        p += (bytes + 255) & ~(size_t)255;
        return r;
    };
    float* X      = (float*)carve((size_t)80000 * 128 * 4);  // pooled x (<= 80000 rows)
    float* Y      = (float*)carve((size_t)100000 * 128 * 4); // y, then h
    float* G      = (float*)carve((size_t)100000 * 128 * 4); // aggr
    int*   E2s    = (int*)carve((size_t)E * 4);
    int*   E2d    = (int*)carve((size_t)E * 4);
    int*   csr    = (int*)carve((size_t)E * 4);
    int*   deg    = (int*)carve(100000 * 4);
    int*   rowptr = (int*)carve(100000 * 4);
    int*   cursor = (int*)carve(100000 * 4);
    int*   bsum   = (int*)carve(256 * 4);
    ull*   keys   = (ull*)carve((size_t)100000 * 8);
    float* sc     = (float*)carve(100000 * 4);
    int*   newpos = (int*)carve(100000 * 4);
    int*   oldidx = (int*)carve(80000 * 4);
    uint*  zmaxu  = (uint*)carve(1024 * 4);
    float* zsum   = (float*)carve(1024 * 4);
    float* z      = (float*)carve(2048 * 4);

    hipMemsetAsync(z, 0, 2048 * 4, stream);

    const float* xin = x0;
    const int* es = e0;
    const int* ed = e0 + E;
    int M = N;
    int eb = (E + 255) / 256;

    for (int l = 0; l < 3; ++l) {
        int n = M / B;
        int k = (int)ceil(0.8 * (double)n);
        int Mout = B * k;
        const float* Wlin = (const float*)d_in[2 + 4 * l];
        const float* blin = (const float*)d_in[3 + 4 * l];
        const float* Wupd = (const float*)d_in[4 + 4 * l];
        const float* wp   = (const float*)d_in[5 + 4 * l];
        int gb = (M + 127) / 128;
        int nb = (M + 1023) / 1024;

        // conv
        gemm_relu<128><<<gb, 256, 0, stream>>>(xin, nullptr, Wlin, blin, Y, M);
        hipMemsetAsync(deg, 0, (size_t)M * 4, stream);
        edge_hist<<<eb, 256, 0, stream>>>(es, ed, deg, E, M);
        scan_a<<<nb, 256, 0, stream>>>(deg, rowptr, bsum, M);
        scan_b<<<1, 256, 0, stream>>>(bsum, nb);
        scan_c<<<(M + 255) / 256, 256, 0, stream>>>(rowptr, cursor, bsum, M);
        edge_place<<<eb, 256, 0, stream>>>(es, ed, cursor, csr, E, M);
        aggr_max<<<(M + 3) / 4, 256, 0, stream>>>(Y, rowptr, deg, csr, G, M);
        gemm_relu<256><<<gb, 256, 0, stream>>>(G, xin, Wupd, nullptr, Y, M);

        // pool
        score_kernel<<<(M + 3) / 4, 256, 0, stream>>>(Y, wp, sc, M);
        topk_kernel<<<B, 1024, 0, stream>>>(sc, keys, newpos, oldidx, n, k, Mout);
        permute_kernel<<<(Mout + 3) / 4, 256, 0, stream>>>(Y, sc, oldidx, X, Mout);

        // readout (accumulate into z)
        hipMemsetAsync(zmaxu, 0, 1024 * 4, stream);
        hipMemsetAsync(zsum, 0, 1024 * 4, stream);
        int chunk = (k + 31) / 32;
        readout_kernel<<<256, 128, 0, stream>>>(X, zmaxu, zsum, k, chunk);
        accum_kernel<<<4, 256, 0, stream>>>(zmaxu, zsum, z, k);

        if (l < 2) {
            remap_kernel<<<eb, 256, 0, stream>>>(es, ed, E2s, E2d, newpos, E, M, Mout);
            es = E2s; ed = E2d;
        }
        xin = X;
        M = Mout;
    }

    mlp_kernel<<<1, 256, 0, stream>>>(z,
        (const float*)d_in[14], (const float*)d_in[15],
        (const float*)d_in[16], (const float*)d_in[17],
        (const float*)d_in[18], (const float*)d_in[19],
        (float*)d_out);
}